// Round 11
// baseline (477.913 us; speedup 1.0000x reference)
//
#include <hip/hip_runtime.h>
#include <hip/hip_fp16.h>

#define N_NODES 100000
#define N_EDGES 3200000
#define F_IN    61
#define F_HID   16
#define F_OUT   2
#define HB      256                    // edge chunks
#define CHUNK   (N_EDGES / HB)         // 12500
#define BSIZE   128                    // nodes per dst-bucket
#define NBUCK   782                    // ceil(N_NODES / BSIZE)

typedef unsigned int uint;

// ---------------- layer-1 node transforms ----------------
// hp[n][c] = half2(h0[c], h1[c]);  r1[n][c] = (x @ root1 + b1)[c]  (f32)
__global__ __launch_bounds__(128) void k_transform1(
    const float* __restrict__ x, const float* __restrict__ W1,
    const float* __restrict__ root1, const float* __restrict__ b1,
    __half2* __restrict__ hp, float* __restrict__ r1)
{
    __shared__ float xs[128 * F_IN];
    __shared__ float w0s[F_IN * F_HID];
    __shared__ float w1s[F_IN * F_HID];
    __shared__ float rs [F_IN * F_HID];
    __shared__ float bs [F_HID];

    const int tid = threadIdx.x;
    for (int i = tid; i < F_IN * F_HID; i += 128) {
        w0s[i] = W1[i];
        w1s[i] = W1[F_IN * F_HID + i];
        rs[i]  = root1[i];
    }
    if (tid < F_HID) bs[tid] = b1[tid];

    const int n0 = blockIdx.x * 128;
    const int nodes = min(128, N_NODES - n0);
    for (int i = tid; i < nodes * F_IN; i += 128)
        xs[i] = x[(size_t)n0 * F_IN + i];
    __syncthreads();

    if (tid < nodes) {
        const int n = n0 + tid;
        float a0[F_HID], a1[F_HID], ar[F_HID];
        #pragma unroll
        for (int c = 0; c < F_HID; ++c) { a0[c] = 0.f; a1[c] = 0.f; ar[c] = 0.f; }
        const float* xr = &xs[tid * F_IN];
        for (int f = 0; f < F_IN; ++f) {
            const float xv = xr[f];
            #pragma unroll
            for (int c = 0; c < F_HID; ++c) {
                a0[c] = fmaf(xv, w0s[f * F_HID + c], a0[c]);
                a1[c] = fmaf(xv, w1s[f * F_HID + c], a1[c]);
                ar[c] = fmaf(xv, rs [f * F_HID + c], ar[c]);
            }
        }
        #pragma unroll
        for (int c = 0; c < F_HID; ++c) {
            hp[(size_t)n * F_HID + c] = __floats2half2_rn(a0[c], a1[c]);
            r1[(size_t)n * F_HID + c] = ar[c] + bs[c];
        }
    }
}

// ---------------- per-(chunk,bucket) counts ----------------
__global__ __launch_bounds__(1024) void k_bhist(
    const int* __restrict__ edst, uint* __restrict__ cnt)
{
    __shared__ uint bins[NBUCK];
    const int bx = blockIdx.x, tid = threadIdx.x;
    for (int i = tid; i < NBUCK; i += 1024) bins[i] = 0;
    __syncthreads();
    const int e0 = bx * CHUNK, e1 = e0 + CHUNK;
    for (int e = e0 + tid; e < e1; e += 1024)
        atomicAdd(&bins[((uint)edst[e]) >> 7], 1u);
    __syncthreads();
    for (int i = tid; i < NBUCK; i += 1024) cnt[(size_t)i * HB + bx] = bins[i];
}

// ---- scan 1: per-bucket LDS scan over its chunk row; emit bucket total ----
__global__ __launch_bounds__(256) void k_brow1(
    uint* __restrict__ cnt, uint* __restrict__ tot)
{
    __shared__ uint s[256];
    const int b = blockIdx.x, tid = threadIdx.x;   // HB == 256
    const uint v = cnt[(size_t)b * HB + tid];
    s[tid] = v; __syncthreads();
    for (int off = 1; off < 256; off <<= 1) {
        const uint t = (tid >= off) ? s[tid - off] : 0u;
        __syncthreads();
        s[tid] += t;
        __syncthreads();
    }
    cnt[(size_t)b * HB + tid] = s[tid] - v;        // exclusive within bucket
    if (tid == 255) tot[b] = s[255];
}

// ---- scan 2: exclusive scan of bucket totals -> bstart --------------------
__global__ __launch_bounds__(1024) void k_bexc(
    const uint* __restrict__ tot, uint* __restrict__ bstart)
{
    __shared__ uint s[1024];
    const int tid = threadIdx.x;
    const uint v = (tid < NBUCK) ? tot[tid] : 0u;
    s[tid] = v; __syncthreads();
    for (int off = 1; off < 1024; off <<= 1) {
        const uint t = (tid >= off) ? s[tid - off] : 0u;
        __syncthreads();
        s[tid] += t;
        __syncthreads();
    }
    if (tid < NBUCK) bstart[tid] = s[tid] - v;
    if (tid == 0) bstart[NBUCK] = N_EDGES;
}

// ---- scan 3: add bucket base to each chunk offset -------------------------
__global__ __launch_bounds__(256) void k_brow2(
    uint* __restrict__ cnt, const uint* __restrict__ bstart)
{
    const int b = blockIdx.x, tid = threadIdx.x;
    cnt[(size_t)b * HB + tid] += bstart[b];
}

// ---- bucket scatter: append each edge to its bucket stream ----------------
// buck entry: .x = src(17b) | dst_local(7b) << 17, .y = attr bits (f32)
__global__ __launch_bounds__(1024) void k_bscatter(
    const int* __restrict__ esrc, const int* __restrict__ edst,
    const float* __restrict__ attr, const uint* __restrict__ cnt,
    uint2* __restrict__ buck)
{
    __shared__ uint pos[NBUCK];
    const int bx = blockIdx.x, tid = threadIdx.x;
    for (int i = tid; i < NBUCK; i += 1024) pos[i] = cnt[(size_t)i * HB + bx];
    __syncthreads();
    const int e0 = bx * CHUNK, e1 = e0 + CHUNK;
    for (int e = e0 + tid; e < e1; e += 1024) {
        const uint d = (uint)edst[e];
        const uint p = atomicAdd(&pos[d >> 7], 1u);
        buck[p] = make_uint2((uint)esrc[e] | ((d & 127u) << 17),
                             __float_as_uint(attr[e]));
    }
}

// ---------------- layer-1 bucket-push aggregate ----------------------------
// block per bucket; 8 lanes/edge gather hp[src] (8B/lane), f32 LDS atomics
// into the bucket accumulator. No CSR, no per-node ordering needed.
__global__ __launch_bounds__(512) void k_bagg1(
    const uint2* __restrict__ buck, const uint* __restrict__ bstart,
    const uint2* __restrict__ hp2, float* __restrict__ sum1,
    uint* __restrict__ deg)
{
    __shared__ float s[BSIZE * F_HID];   // 8 KB
    __shared__ uint  cl[BSIZE];
    const int b = blockIdx.x, tid = threadIdx.x;
    const uint e0 = bstart[b], e1 = bstart[b + 1];
    for (int i = tid; i < BSIZE * F_HID; i += 512) s[i] = 0.f;
    if (tid < BSIZE) cl[tid] = 0u;
    __syncthreads();

    const int g = tid >> 3;     // edge group 0..63
    const int q = tid & 7;      // feature pair: features 2q, 2q+1
    #pragma unroll 4
    for (uint e = e0 + g; e < e1; e += 64) {
        const uint2 w = buck[e];
        const uint dl = (w.x >> 17) & 127u;
        const float u = __uint_as_float(w.y);
        const uint2 hw = hp2[(size_t)(w.x & 0x1FFFFu) * 8 + q];
        const float2 ha = __half22float2(*(const __half2*)&hw.x);
        const float2 hb = __half22float2(*(const __half2*)&hw.y);
        atomicAdd(&s[dl * F_HID + 2 * q],     (1.0f - u) * ha.x + u * ha.y);
        atomicAdd(&s[dl * F_HID + 2 * q + 1], (1.0f - u) * hb.x + u * hb.y);
        if (q == 0) atomicAdd(&cl[dl], 1u);
    }
    __syncthreads();

    const int n0 = b * BSIZE;
    const int nodes = min(BSIZE, N_NODES - n0);
    for (int i = tid; i < nodes * F_HID; i += 512)
        sum1[(size_t)n0 * F_HID + i] = s[i];
    if (tid < nodes) deg[n0 + tid] = cl[tid];
}

// ---------------- dense per-node finalize: mean + ELU + layer-2 transforms -
__global__ __launch_bounds__(256) void k_mid2(
    const float* __restrict__ sum1, const uint* __restrict__ deg,
    const float* __restrict__ r1,
    const float* __restrict__ W2, const float* __restrict__ root2,
    const float* __restrict__ b2,
    float4* __restrict__ h2, float2* __restrict__ r2)
{
    __shared__ float w2s[2 * F_HID * F_OUT];
    __shared__ float rts[F_HID * F_OUT];
    __shared__ float b2s[F_OUT];
    const int tid = threadIdx.x;
    if (tid < 2 * F_HID * F_OUT) w2s[tid] = W2[tid];
    if (tid < F_HID * F_OUT)     rts[tid] = root2[tid];
    if (tid < F_OUT)             b2s[tid] = b2[tid];
    __syncthreads();

    const int n = blockIdx.x * 256 + tid;
    if (n >= N_NODES) return;

    const float inv = 1.0f / (float)max(deg[n], 1u);

    float h[F_HID];
    #pragma unroll
    for (int k = 0; k < F_HID; ++k) {
        const float v = sum1[(size_t)n * F_HID + k] * inv + r1[(size_t)n * F_HID + k];
        h[k] = (v > 0.0f) ? v : expm1f(v);   // ELU
    }
    float o00 = 0.f, o01 = 0.f, o10 = 0.f, o11 = 0.f;
    float rr0 = b2s[0], rr1 = b2s[1];
    #pragma unroll
    for (int f = 0; f < F_HID; ++f) {
        o00 = fmaf(h[f], w2s[f * 2 + 0], o00);
        o01 = fmaf(h[f], w2s[f * 2 + 1], o01);
        o10 = fmaf(h[f], w2s[2 * F_HID + f * 2 + 0], o10);
        o11 = fmaf(h[f], w2s[2 * F_HID + f * 2 + 1], o11);
        rr0 = fmaf(h[f], rts[f * 2 + 0], rr0);
        rr1 = fmaf(h[f], rts[f * 2 + 1], rr1);
    }
    h2[n] = make_float4(o00, o10, o01, o11);   // (k0o0, k1o0, k0o1, k1o1)
    r2[n] = make_float2(rr0, rr1);
}

// ---------------- layer-2 bucket-push aggregate + log_softmax --------------
__global__ __launch_bounds__(512) void k_bagg2(
    const uint2* __restrict__ buck, const uint* __restrict__ bstart,
    const float4* __restrict__ h2, const uint* __restrict__ deg,
    const float2* __restrict__ r2, float2* __restrict__ out)
{
    __shared__ float s2[BSIZE * 2];      // 1 KB
    const int b = blockIdx.x, tid = threadIdx.x;
    const uint e0 = bstart[b], e1 = bstart[b + 1];
    if (tid < BSIZE * 2) s2[tid] = 0.f;
    __syncthreads();

    #pragma unroll 4
    for (uint e = e0 + tid; e < e1; e += 512) {
        const uint2 w = buck[e];
        const uint dl = (w.x >> 17) & 127u;
        const float u = __uint_as_float(w.y);
        const float4 h = h2[w.x & 0x1FFFFu];
        atomicAdd(&s2[dl * 2 + 0], (1.0f - u) * h.x + u * h.y);
        atomicAdd(&s2[dl * 2 + 1], (1.0f - u) * h.z + u * h.w);
    }
    __syncthreads();

    const int n = b * BSIZE + tid;
    if (tid < BSIZE && n < N_NODES) {
        const float inv = 1.0f / (float)max(deg[n], 1u);
        const float2 rr = r2[n];
        const float o0 = s2[tid * 2 + 0] * inv + rr.x;
        const float o1 = s2[tid * 2 + 1] * inv + rr.y;
        const float m  = fmaxf(o0, o1);
        const float l  = m + logf(expf(o0 - m) + expf(o1 - m));
        out[n] = make_float2(o0 - l, o1 - l);
    }
}

extern "C" void kernel_launch(void* const* d_in, const int* in_sizes, int n_in,
                              void* d_out, int out_size, void* d_ws, size_t ws_size,
                              hipStream_t stream) {
    const float* x     = (const float*)d_in[0];
    const int*   ei    = (const int*)  d_in[1];   // [2][N_EDGES]
    const float* attr  = (const float*)d_in[2];
    const float* W1    = (const float*)d_in[4];
    const float* root1 = (const float*)d_in[5];
    const float* b1    = (const float*)d_in[6];
    const float* W2    = (const float*)d_in[7];
    const float* root2 = (const float*)d_in[8];
    const float* b2    = (const float*)d_in[9];
    float2* out = (float2*)d_out;

    char* ws = (char*)d_ws;
    size_t off = 0;
    uint2*   buck  = (uint2*)  (ws + off); off += (size_t)N_EDGES * sizeof(uint2);           // 25.6MB
    uint*    cnt   = (uint*)   (ws + off); off += (size_t)NBUCK * HB * sizeof(uint);         // 800KB
    uint*    bstart= (uint*)   (ws + off); off += (size_t)(NBUCK + 1) * sizeof(uint);
    uint*    tot   = (uint*)   (ws + off); off += (size_t)NBUCK * sizeof(uint);
    uint*    deg   = (uint*)   (ws + off); off += (size_t)N_NODES * sizeof(uint);            // 400KB
    off = (off + 255) & ~(size_t)255;
    __half2* hp    = (__half2*)(ws + off); off += (size_t)N_NODES * F_HID * sizeof(__half2); // 6.4MB
    float*   r1    = (float*)  (ws + off); off += (size_t)N_NODES * F_HID * sizeof(float);   // 6.4MB
    float*   sum1  = (float*)  (ws + off); off += (size_t)N_NODES * F_HID * sizeof(float);   // 6.4MB
    float4*  h2    = (float4*) (ws + off); off += (size_t)N_NODES * sizeof(float4);          // 1.6MB
    float2*  r2    = (float2*) (ws + off); off += (size_t)N_NODES * sizeof(float2);          // 0.8MB

    const int* esrc = ei;
    const int* edst = ei + N_EDGES;

    k_bhist    <<<HB, 1024, 0, stream>>>(edst, cnt);
    k_brow1    <<<NBUCK, 256, 0, stream>>>(cnt, tot);
    k_bexc     <<<1, 1024, 0, stream>>>(tot, bstart);
    k_brow2    <<<NBUCK, 256, 0, stream>>>(cnt, bstart);
    k_bscatter <<<HB, 1024, 0, stream>>>(esrc, edst, attr, cnt, buck);
    k_transform1<<<(N_NODES + 127) / 128, 128, 0, stream>>>(x, W1, root1, b1, hp, r1);
    k_bagg1    <<<NBUCK, 512, 0, stream>>>(buck, bstart, (const uint2*)hp, sum1, deg);
    k_mid2     <<<(N_NODES + 255) / 256, 256, 0, stream>>>(sum1, deg, r1, W2, root2, b2, h2, r2);
    k_bagg2    <<<NBUCK, 512, 0, stream>>>(buck, bstart, h2, deg, r2, out);
}

// Round 12
// 202.339 us; speedup vs baseline: 2.3619x; 2.3619x over previous
//
#include <hip/hip_runtime.h>
#include <hip/hip_fp16.h>

#define N_NODES 100000
#define N_EDGES 3200000
#define F_IN    61
#define F_HID   16
#define F_OUT   2
#define HB      256                    // edge chunks
#define CHUNK   (N_EDGES / HB)         // 12500
#define BSIZE   512                    // nodes per dst-bucket
#define NBUCK   196                    // ceil(N_NODES / BSIZE)

typedef unsigned int uint;
typedef unsigned short ushort;

// ---------------- layer-1 node transforms ----------------
// hp[n][c] = half2(h0[c], h1[c]);  r1[n][c] = (x @ root1 + b1)[c]  (f32)
__global__ __launch_bounds__(128) void k_transform1(
    const float* __restrict__ x, const float* __restrict__ W1,
    const float* __restrict__ root1, const float* __restrict__ b1,
    __half2* __restrict__ hp, float* __restrict__ r1)
{
    __shared__ float xs[128 * F_IN];
    __shared__ float w0s[F_IN * F_HID];
    __shared__ float w1s[F_IN * F_HID];
    __shared__ float rs [F_IN * F_HID];
    __shared__ float bs [F_HID];

    const int tid = threadIdx.x;
    for (int i = tid; i < F_IN * F_HID; i += 128) {
        w0s[i] = W1[i];
        w1s[i] = W1[F_IN * F_HID + i];
        rs[i]  = root1[i];
    }
    if (tid < F_HID) bs[tid] = b1[tid];

    const int n0 = blockIdx.x * 128;
    const int nodes = min(128, N_NODES - n0);
    for (int i = tid; i < nodes * F_IN; i += 128)
        xs[i] = x[(size_t)n0 * F_IN + i];
    __syncthreads();

    if (tid < nodes) {
        const int n = n0 + tid;
        float a0[F_HID], a1[F_HID], ar[F_HID];
        #pragma unroll
        for (int c = 0; c < F_HID; ++c) { a0[c] = 0.f; a1[c] = 0.f; ar[c] = 0.f; }
        const float* xr = &xs[tid * F_IN];
        for (int f = 0; f < F_IN; ++f) {
            const float xv = xr[f];
            #pragma unroll
            for (int c = 0; c < F_HID; ++c) {
                a0[c] = fmaf(xv, w0s[f * F_HID + c], a0[c]);
                a1[c] = fmaf(xv, w1s[f * F_HID + c], a1[c]);
                ar[c] = fmaf(xv, rs [f * F_HID + c], ar[c]);
            }
        }
        #pragma unroll
        for (int c = 0; c < F_HID; ++c) {
            hp[(size_t)n * F_HID + c] = __floats2half2_rn(a0[c], a1[c]);
            r1[(size_t)n * F_HID + c] = ar[c] + bs[c];
        }
    }
}

// ---------------- phase A: per-(chunk,bucket) counts ----------------
__global__ __launch_bounds__(1024) void k_bhist(
    const int* __restrict__ edst, uint* __restrict__ cnt)
{
    __shared__ uint bins[NBUCK];
    const int bx = blockIdx.x, tid = threadIdx.x;
    for (int i = tid; i < NBUCK; i += 1024) bins[i] = 0;
    __syncthreads();
    const int e0 = bx * CHUNK, e1 = e0 + CHUNK;
    for (int e = e0 + tid; e < e1; e += 1024)
        atomicAdd(&bins[((uint)edst[e]) >> 9], 1u);
    __syncthreads();
    for (int i = tid; i < NBUCK; i += 1024) cnt[(size_t)i * HB + bx] = bins[i];
}

// ---- scan 1: per-bucket LDS scan over its chunk row; emit bucket total ----
__global__ __launch_bounds__(256) void k_brow1(
    uint* __restrict__ cnt, uint* __restrict__ tot)
{
    __shared__ uint s[256];
    const int b = blockIdx.x, tid = threadIdx.x;   // HB == 256
    const uint v = cnt[(size_t)b * HB + tid];
    s[tid] = v; __syncthreads();
    for (int off = 1; off < 256; off <<= 1) {
        const uint t = (tid >= off) ? s[tid - off] : 0u;
        __syncthreads();
        s[tid] += t;
        __syncthreads();
    }
    cnt[(size_t)b * HB + tid] = s[tid] - v;        // exclusive within bucket
    if (tid == 255) tot[b] = s[255];
}

// ---- scan 2: exclusive scan of bucket totals -> bstart --------------------
__global__ __launch_bounds__(256) void k_bexc(
    const uint* __restrict__ tot, uint* __restrict__ bstart)
{
    __shared__ uint s[256];
    const int tid = threadIdx.x;
    const uint v = (tid < NBUCK) ? tot[tid] : 0u;
    s[tid] = v; __syncthreads();
    for (int off = 1; off < 256; off <<= 1) {
        const uint t = (tid >= off) ? s[tid - off] : 0u;
        __syncthreads();
        s[tid] += t;
        __syncthreads();
    }
    if (tid < NBUCK) bstart[tid] = s[tid] - v;
    if (tid == 0) bstart[NBUCK] = N_EDGES;
}

// ---- phase A scatter: append each edge to its bucket stream --------------
// pos seeded with cnt + bstart (brow2 folded in). Key/u split arrays:
// key = src(17b) | dst_local(9b)<<17;  u pre-quantized to 15 bits in u16.
__global__ __launch_bounds__(1024) void k_bscatter(
    const int* __restrict__ esrc, const int* __restrict__ edst,
    const float* __restrict__ attr, const uint* __restrict__ cnt,
    const uint* __restrict__ bstart,
    uint* __restrict__ buckKey, ushort* __restrict__ buckU)
{
    __shared__ uint pos[NBUCK];
    const int bx = blockIdx.x, tid = threadIdx.x;
    for (int i = tid; i < NBUCK; i += 1024)
        pos[i] = cnt[(size_t)i * HB + bx] + bstart[i];
    __syncthreads();
    const int e0 = bx * CHUNK, e1 = e0 + CHUNK;
    for (int e = e0 + tid; e < e1; e += 1024) {
        const uint d = (uint)edst[e];
        const uint p = atomicAdd(&pos[d >> 9], 1u);
        buckKey[p] = (uint)esrc[e] | ((d & 511u) << 17);
        buckU[p]   = (ushort)(attr[e] * 32767.0f + 0.5f);
    }
}

// ---- phase B: per-bucket local count+scan -> rowptr, then dense scatter ---
// vals entry packs src(17b) << 15 | u_q(15b).
__global__ __launch_bounds__(1024) void k_fscatter(
    const uint* __restrict__ buckKey, const ushort* __restrict__ buckU,
    const uint* __restrict__ bstart,
    uint* __restrict__ rowptr, uint* __restrict__ vals)
{
    __shared__ uint deg[BSIZE];     // then running positions
    __shared__ uint excl[BSIZE];
    const int b = blockIdx.x, tid = threadIdx.x;
    const uint e0 = bstart[b], e1 = bstart[b + 1];

    for (int i = tid; i < BSIZE; i += 1024) deg[i] = 0;
    __syncthreads();
    for (uint e = e0 + tid; e < e1; e += 1024)
        atomicAdd(&deg[(buckKey[e] >> 17) & 511u], 1u);
    __syncthreads();

    if (tid < BSIZE) excl[tid] = deg[tid];
    __syncthreads();
    for (int off = 1; off < BSIZE; off <<= 1) {
        uint t = 0;
        if (tid < BSIZE && tid >= off) t = excl[tid - off];
        __syncthreads();
        if (tid < BSIZE) excl[tid] += t;
        __syncthreads();
    }
    if (tid < BSIZE) {
        const uint ex = excl[tid] - deg[tid];   // exclusive prefix
        const int n = b * BSIZE + tid;
        if (n < N_NODES) rowptr[n] = e0 + ex;
        deg[tid] = ex;                          // reuse as running position
    }
    if (b == 0 && tid == 0) rowptr[N_NODES] = N_EDGES;
    __syncthreads();

    for (uint e = e0 + tid; e < e1; e += 1024) {
        const uint k = buckKey[e];
        const uint dl = (k >> 17) & 511u;
        const uint p = atomicAdd(&deg[dl], 1u);
        vals[e0 + p] = ((k & 0x1FFFFu) << 15) | (uint)buckU[e];
    }
}

// ---------------- layer-1 pull aggregate (lean): sums only -----------------
// wave per node; lanes = 8 edge-slots x 8 feature-pairs. Packed f16 FMA.
// Per-node finalize (mean/ELU/transform) in dense k_mid2.
__global__ __launch_bounds__(256) void k_agg1(
    const uint* __restrict__ rowptr, const uint* __restrict__ vals,
    const uint2* __restrict__ hp2, float2* __restrict__ sum1)
{
    __shared__ uint ent[4][64];         // 1 KB: per-wave CSR entry stage
    const int tid = threadIdx.x;
    const int lane = tid & 63;
    const int wave = tid >> 6;
    const int n = blockIdx.x * 4 + wave;
    const int ep = lane >> 3;          // edge slot 0..7
    const int q  = lane & 7;           // feature pair: features 2q, 2q+1

    const uint r0 = rowptr[n];
    const uint deg = rowptr[n + 1] - r0;
    const uint dcap = min(deg, 64u);

    if ((uint)lane < dcap)
        ent[wave][lane] = __builtin_nontemporal_load(&vals[r0 + lane]);
    __syncthreads();

    __half2 acc_a = __float2half2_rn(0.f);
    __half2 acc_b = __float2half2_rn(0.f);
    #pragma unroll 4
    for (uint i = ep; i < dcap; i += 8) {
        const uint v  = ent[wave][i];
        const float uu = (float)(v & 32767u) * (1.0f / 32767.0f);
        const __half2 wv = __floats2half2_rn(1.0f - uu, uu);
        const uint2 hw = hp2[(size_t)(v >> 15) * 8 + q];
        acc_a = __hfma2(wv, *(const __half2*)&hw.x, acc_a);
        acc_b = __hfma2(wv, *(const __half2*)&hw.y, acc_b);
    }
    for (uint i = 64 + ep; i < deg; i += 8) {    // rare overflow tail
        const uint v  = __builtin_nontemporal_load(&vals[r0 + i]);
        const float uu = (float)(v & 32767u) * (1.0f / 32767.0f);
        const __half2 wv = __floats2half2_rn(1.0f - uu, uu);
        const uint2 hw = hp2[(size_t)(v >> 15) * 8 + q];
        acc_a = __hfma2(wv, *(const __half2*)&hw.x, acc_a);
        acc_b = __hfma2(wv, *(const __half2*)&hw.y, acc_b);
    }
    const float2 fa = __half22float2(acc_a);
    const float2 fb = __half22float2(acc_b);
    float a0 = fa.x + fa.y;            // Σ (1-u)*h0 + u*h1, feature 2q
    float a1 = fb.x + fb.y;            // feature 2q+1
    a0 += __shfl_xor(a0, 8); a0 += __shfl_xor(a0, 16); a0 += __shfl_xor(a0, 32);
    a1 += __shfl_xor(a1, 8); a1 += __shfl_xor(a1, 16); a1 += __shfl_xor(a1, 32);

    if (lane < 8)
        sum1[(size_t)n * 8 + lane] = make_float2(a0, a1);
}

// ---------------- dense per-node finalize: mean + ELU + layer-2 transforms -
__global__ __launch_bounds__(256) void k_mid2(
    const float2* __restrict__ sum1, const uint* __restrict__ rowptr,
    const float* __restrict__ r1,
    const float* __restrict__ W2, const float* __restrict__ root2,
    const float* __restrict__ b2,
    float4* __restrict__ h2, float2* __restrict__ r2)
{
    __shared__ float w2s[2 * F_HID * F_OUT];
    __shared__ float rts[F_HID * F_OUT];
    __shared__ float b2s[F_OUT];
    const int tid = threadIdx.x;
    if (tid < 2 * F_HID * F_OUT) w2s[tid] = W2[tid];
    if (tid < F_HID * F_OUT)     rts[tid] = root2[tid];
    if (tid < F_OUT)             b2s[tid] = b2[tid];
    __syncthreads();

    const int n = blockIdx.x * 256 + tid;
    if (n >= N_NODES) return;

    const uint deg = rowptr[n + 1] - rowptr[n];
    const float inv = 1.0f / (float)max(deg, 1u);

    float h[F_HID];
    #pragma unroll
    for (int k = 0; k < 8; ++k) {
        const float2 s = sum1[(size_t)n * 8 + k];
        const float v0 = s.x * inv + r1[(size_t)n * F_HID + 2 * k];
        const float v1 = s.y * inv + r1[(size_t)n * F_HID + 2 * k + 1];
        h[2 * k]     = (v0 > 0.0f) ? v0 : expm1f(v0);   // ELU
        h[2 * k + 1] = (v1 > 0.0f) ? v1 : expm1f(v1);
    }
    float o00 = 0.f, o01 = 0.f, o10 = 0.f, o11 = 0.f;
    float rr0 = b2s[0], rr1 = b2s[1];
    #pragma unroll
    for (int f = 0; f < F_HID; ++f) {
        o00 = fmaf(h[f], w2s[f * 2 + 0], o00);
        o01 = fmaf(h[f], w2s[f * 2 + 1], o01);
        o10 = fmaf(h[f], w2s[2 * F_HID + f * 2 + 0], o10);
        o11 = fmaf(h[f], w2s[2 * F_HID + f * 2 + 1], o11);
        rr0 = fmaf(h[f], rts[f * 2 + 0], rr0);
        rr1 = fmaf(h[f], rts[f * 2 + 1], rr1);
    }
    h2[n] = make_float4(o00, o10, o01, o11);   // [out0:(k0,k1), out1:(k0,k1)]
    r2[n] = make_float2(rr0, rr1);
}

// ---------------- layer-2 pull aggregate + log_softmax --------------------
// wave per node; lanes = 32 edge-slots x 2 features; LDS-staged u32 entries.
__global__ __launch_bounds__(256) void k_agg2(
    const uint* __restrict__ rowptr, const uint* __restrict__ vals,
    const float2* __restrict__ h2f2, const float2* __restrict__ r2,
    float* __restrict__ out)
{
    __shared__ uint ent[4][64];         // 1 KB
    const int tid = threadIdx.x;
    const int lane = tid & 63;
    const int wave = tid >> 6;
    const int n = blockIdx.x * 4 + wave;
    const int ep = lane >> 1;          // 0..31
    const int fp = lane & 1;           // feature

    const uint r0 = rowptr[n];
    const uint deg = rowptr[n + 1] - r0;
    const uint dcap = min(deg, 64u);

    if ((uint)lane < dcap)
        ent[wave][lane] = __builtin_nontemporal_load(&vals[r0 + lane]);
    __syncthreads();

    float acc = 0.f;
    #pragma unroll 2
    for (uint i = ep; i < dcap; i += 32) {
        const uint v  = ent[wave][i];
        const float uu = (float)(v & 32767u) * (1.0f / 32767.0f);
        const float2 g = h2f2[(size_t)(v >> 15) * 2 + fp];
        acc += (1.0f - uu) * g.x + uu * g.y;
    }
    for (uint i = 64 + ep; i < deg; i += 32) {   // rare overflow tail
        const uint v  = __builtin_nontemporal_load(&vals[r0 + i]);
        const float uu = (float)(v & 32767u) * (1.0f / 32767.0f);
        const float2 g = h2f2[(size_t)(v >> 15) * 2 + fp];
        acc += (1.0f - uu) * g.x + uu * g.y;
    }
    #pragma unroll
    for (int off = 2; off < 64; off <<= 1) acc += __shfl_xor(acc, off);

    const float inv = 1.0f / (float)max(deg, 1u);
    const float rv = fp ? r2[n].y : r2[n].x;
    const float o = acc * inv + rv;
    const float other = __shfl_xor(o, 1);
    const float m = fmaxf(o, other);
    const float l = m + logf(expf(o - m) + expf(other - m));
    if (lane < 2) out[(size_t)n * 2 + fp] = o - l;
}

extern "C" void kernel_launch(void* const* d_in, const int* in_sizes, int n_in,
                              void* d_out, int out_size, void* d_ws, size_t ws_size,
                              hipStream_t stream) {
    const float* x     = (const float*)d_in[0];
    const int*   ei    = (const int*)  d_in[1];   // [2][N_EDGES]
    const float* attr  = (const float*)d_in[2];
    const float* W1    = (const float*)d_in[4];
    const float* root1 = (const float*)d_in[5];
    const float* b1    = (const float*)d_in[6];
    const float* W2    = (const float*)d_in[7];
    const float* root2 = (const float*)d_in[8];
    const float* b2    = (const float*)d_in[9];
    float* out = (float*)d_out;

    char* ws = (char*)d_ws;
    size_t off = 0;
    uint*   vals   = (uint*)  (ws + off); off += (size_t)N_EDGES * sizeof(uint);         // 12.8MB
    uint*   rowptr = (uint*)  (ws + off); off += (size_t)(N_NODES + 1) * sizeof(uint);
    uint*   cnt    = (uint*)  (ws + off); off += (size_t)NBUCK * HB * sizeof(uint);      // 200KB
    uint*   bstart = (uint*)  (ws + off); off += (size_t)(NBUCK + 1) * sizeof(uint);
    uint*   tot    = (uint*)  (ws + off); off += (size_t)NBUCK * sizeof(uint);
    off = (off + 255) & ~(size_t)255;
    uint*   buckKey= (uint*)  (ws + off);                                                // 12.8MB
    ushort* buckU  = (ushort*)(ws + off + (size_t)N_EDGES * sizeof(uint));               // 6.4MB
    // buckKey/buckU are dead after k_fscatter; alias node buffers over the
    // same region (21.6MB needed > 19.2MB of buck, so reserve the max).
    char* alias = ws + off;
    size_t aoff = 0;
    __half2* hp = (__half2*)(alias + aoff); aoff += (size_t)N_NODES * F_HID * sizeof(__half2); // 6.4MB
    float*   r1 = (float*)  (alias + aoff); aoff += (size_t)N_NODES * F_HID * sizeof(float);   // 6.4MB
    float4*  h2 = (float4*) (alias + aoff); aoff += (size_t)N_NODES * sizeof(float4);          // 1.6MB
    float2*  r2 = (float2*) (alias + aoff); aoff += (size_t)N_NODES * sizeof(float2);          // 0.8MB
    float2* sum1= (float2*) (alias + aoff); aoff += (size_t)N_NODES * 8 * sizeof(float2);      // 6.4MB
    (void)ws_size;

    const int* esrc = ei;
    const int* edst = ei + N_EDGES;

    k_bhist    <<<HB, 1024, 0, stream>>>(edst, cnt);
    k_brow1    <<<NBUCK, 256, 0, stream>>>(cnt, tot);
    k_bexc     <<<1, 256, 0, stream>>>(tot, bstart);
    k_bscatter <<<HB, 1024, 0, stream>>>(esrc, edst, attr, cnt, bstart, buckKey, buckU);
    k_fscatter <<<NBUCK, 1024, 0, stream>>>(buckKey, buckU, bstart, rowptr, vals);
    k_transform1<<<(N_NODES + 127) / 128, 128, 0, stream>>>(x, W1, root1, b1, hp, r1);
    k_agg1     <<<N_NODES / 4, 256, 0, stream>>>(rowptr, vals, (const uint2*)hp, sum1);
    k_mid2     <<<(N_NODES + 255) / 256, 256, 0, stream>>>(sum1, rowptr, r1, W2, root2, b2, h2, r2);
    k_agg2     <<<N_NODES / 4, 256, 0, stream>>>(rowptr, vals, (const float2*)h2, r2, out);
}

// Round 13
// 189.207 us; speedup vs baseline: 2.5259x; 1.0694x over previous
//
#include <hip/hip_runtime.h>
#include <hip/hip_fp16.h>

#define N_NODES 100000
#define N_EDGES 3200000
#define F_IN    61
#define F_HID   16
#define F_OUT   2
#define HB      256                    // edge chunks
#define CHUNK   (N_EDGES / HB)         // 12500
#define BSIZE   512                    // nodes per dst-bucket
#define NBUCK   196                    // ceil(N_NODES / BSIZE)

typedef unsigned int uint;

// ---------------- layer-1 node transforms ----------------
// hp[n][c] = half2(h0[c], h1[c]);  r1[n][c] = (x @ root1 + b1)[c]  (f32)
__global__ __launch_bounds__(128) void k_transform1(
    const float* __restrict__ x, const float* __restrict__ W1,
    const float* __restrict__ root1, const float* __restrict__ b1,
    __half2* __restrict__ hp, float* __restrict__ r1)
{
    __shared__ float xs[128 * F_IN];
    __shared__ float w0s[F_IN * F_HID];
    __shared__ float w1s[F_IN * F_HID];
    __shared__ float rs [F_IN * F_HID];
    __shared__ float bs [F_HID];

    const int tid = threadIdx.x;
    for (int i = tid; i < F_IN * F_HID; i += 128) {
        w0s[i] = W1[i];
        w1s[i] = W1[F_IN * F_HID + i];
        rs[i]  = root1[i];
    }
    if (tid < F_HID) bs[tid] = b1[tid];

    const int n0 = blockIdx.x * 128;
    const int nodes = min(128, N_NODES - n0);
    for (int i = tid; i < nodes * F_IN; i += 128)
        xs[i] = x[(size_t)n0 * F_IN + i];
    __syncthreads();

    if (tid < nodes) {
        const int n = n0 + tid;
        float a0[F_HID], a1[F_HID], ar[F_HID];
        #pragma unroll
        for (int c = 0; c < F_HID; ++c) { a0[c] = 0.f; a1[c] = 0.f; ar[c] = 0.f; }
        const float* xr = &xs[tid * F_IN];
        for (int f = 0; f < F_IN; ++f) {
            const float xv = xr[f];
            #pragma unroll
            for (int c = 0; c < F_HID; ++c) {
                a0[c] = fmaf(xv, w0s[f * F_HID + c], a0[c]);
                a1[c] = fmaf(xv, w1s[f * F_HID + c], a1[c]);
                ar[c] = fmaf(xv, rs [f * F_HID + c], ar[c]);
            }
        }
        #pragma unroll
        for (int c = 0; c < F_HID; ++c) {
            hp[(size_t)n * F_HID + c] = __floats2half2_rn(a0[c], a1[c]);
            r1[(size_t)n * F_HID + c] = ar[c] + bs[c];
        }
    }
}

// ---------------- phase A: per-(chunk,bucket) counts ----------------
__global__ __launch_bounds__(1024) void k_bhist(
    const int* __restrict__ edst, uint* __restrict__ cnt)
{
    __shared__ uint bins[NBUCK];
    const int bx = blockIdx.x, tid = threadIdx.x;
    for (int i = tid; i < NBUCK; i += 1024) bins[i] = 0;
    __syncthreads();
    const int e0 = bx * CHUNK, e1 = e0 + CHUNK;
    for (int e = e0 + tid; e < e1; e += 1024)
        atomicAdd(&bins[((uint)edst[e]) >> 9], 1u);
    __syncthreads();
    for (int i = tid; i < NBUCK; i += 1024) cnt[(size_t)i * HB + bx] = bins[i];
}

// ---- scan 1: per-bucket LDS scan over its chunk row; emit bucket total ----
__global__ __launch_bounds__(256) void k_brow1(
    uint* __restrict__ cnt, uint* __restrict__ tot)
{
    __shared__ uint s[256];
    const int b = blockIdx.x, tid = threadIdx.x;   // HB == 256
    const uint v = cnt[(size_t)b * HB + tid];
    s[tid] = v; __syncthreads();
    for (int off = 1; off < 256; off <<= 1) {
        const uint t = (tid >= off) ? s[tid - off] : 0u;
        __syncthreads();
        s[tid] += t;
        __syncthreads();
    }
    cnt[(size_t)b * HB + tid] = s[tid] - v;        // exclusive within bucket
    if (tid == 255) tot[b] = s[255];
}

// ---- scan 2: exclusive scan of bucket totals -> bstart --------------------
__global__ __launch_bounds__(256) void k_bexc(
    const uint* __restrict__ tot, uint* __restrict__ bstart)
{
    __shared__ uint s[256];
    const int tid = threadIdx.x;
    const uint v = (tid < NBUCK) ? tot[tid] : 0u;
    s[tid] = v; __syncthreads();
    for (int off = 1; off < 256; off <<= 1) {
        const uint t = (tid >= off) ? s[tid - off] : 0u;
        __syncthreads();
        s[tid] += t;
        __syncthreads();
    }
    if (tid < NBUCK) bstart[tid] = s[tid] - v;
    if (tid == 0) bstart[NBUCK] = N_EDGES;
}

// ---- phase A scatter: append each edge to its bucket stream --------------
// pos seeded with cnt + bstart (brow2 folded in). Single aligned 8B store
// per edge (uint2) — sub-word / split-stream scatter proven bad (round 12).
__global__ __launch_bounds__(1024) void k_bscatter(
    const int* __restrict__ esrc, const int* __restrict__ edst,
    const float* __restrict__ attr, const uint* __restrict__ cnt,
    const uint* __restrict__ bstart, uint2* __restrict__ buck)
{
    __shared__ uint pos[NBUCK];
    const int bx = blockIdx.x, tid = threadIdx.x;
    for (int i = tid; i < NBUCK; i += 1024)
        pos[i] = cnt[(size_t)i * HB + bx] + bstart[i];
    __syncthreads();
    const int e0 = bx * CHUNK, e1 = e0 + CHUNK;
    for (int e = e0 + tid; e < e1; e += 1024) {
        const uint d = (uint)edst[e];
        const uint p = atomicAdd(&pos[d >> 9], 1u);
        buck[p] = make_uint2((uint)esrc[e] | ((d & 511u) << 17),
                             __float_as_uint(attr[e]));
    }
}

// ---- phase B: per-bucket local count+scan -> rowptr, then dense scatter ---
// vals entry packs src(17b) << 15 | u_q(15b); u_q = round(u * 32767).
__global__ __launch_bounds__(1024) void k_fscatter(
    const uint2* __restrict__ buck, const uint* __restrict__ bstart,
    uint* __restrict__ rowptr, uint* __restrict__ vals)
{
    __shared__ uint deg[BSIZE];     // then running positions
    __shared__ uint excl[BSIZE];
    const int b = blockIdx.x, tid = threadIdx.x;
    const uint e0 = bstart[b], e1 = bstart[b + 1];

    for (int i = tid; i < BSIZE; i += 1024) deg[i] = 0;
    __syncthreads();
    for (uint e = e0 + tid; e < e1; e += 1024)
        atomicAdd(&deg[(buck[e].x >> 17) & 511u], 1u);
    __syncthreads();

    if (tid < BSIZE) excl[tid] = deg[tid];
    __syncthreads();
    for (int off = 1; off < BSIZE; off <<= 1) {
        uint t = 0;
        if (tid < BSIZE && tid >= off) t = excl[tid - off];
        __syncthreads();
        if (tid < BSIZE) excl[tid] += t;
        __syncthreads();
    }
    if (tid < BSIZE) {
        const uint ex = excl[tid] - deg[tid];   // exclusive prefix
        const int n = b * BSIZE + tid;
        if (n < N_NODES) rowptr[n] = e0 + ex;
        deg[tid] = ex;                          // reuse as running position
    }
    if (b == 0 && tid == 0) rowptr[N_NODES] = N_EDGES;
    __syncthreads();

    for (uint e = e0 + tid; e < e1; e += 1024) {
        const uint2 w = buck[e];
        const uint dl = (w.x >> 17) & 511u;
        const uint p = atomicAdd(&deg[dl], 1u);
        const float uf = __uint_as_float(w.y);
        const uint uq = (uint)(uf * 32767.0f + 0.5f);
        vals[e0 + p] = ((w.x & 0x1FFFFu) << 15) | uq;
    }
}

// ---------------- layer-1 pull aggregate (lean): sums only -----------------
// wave per node; lanes = 8 edge-slots x 8 feature-pairs. Packed f16 FMA.
// Per-node finalize (mean/ELU/transform) in dense k_mid2.
__global__ __launch_bounds__(256) void k_agg1(
    const uint* __restrict__ rowptr, const uint* __restrict__ vals,
    const uint2* __restrict__ hp2, float2* __restrict__ sum1)
{
    __shared__ uint ent[4][64];         // 1 KB: per-wave CSR entry stage
    const int tid = threadIdx.x;
    const int lane = tid & 63;
    const int wave = tid >> 6;
    const int n = blockIdx.x * 4 + wave;
    const int ep = lane >> 3;          // edge slot 0..7
    const int q  = lane & 7;           // feature pair: features 2q, 2q+1

    const uint r0 = rowptr[n];
    const uint deg = rowptr[n + 1] - r0;
    const uint dcap = min(deg, 64u);

    if ((uint)lane < dcap)
        ent[wave][lane] = __builtin_nontemporal_load(&vals[r0 + lane]);
    __syncthreads();

    __half2 acc_a = __float2half2_rn(0.f);
    __half2 acc_b = __float2half2_rn(0.f);
    #pragma unroll 4
    for (uint i = ep; i < dcap; i += 8) {
        const uint v  = ent[wave][i];
        const float uu = (float)(v & 32767u) * (1.0f / 32767.0f);
        const __half2 wv = __floats2half2_rn(1.0f - uu, uu);
        const uint2 hw = hp2[(size_t)(v >> 15) * 8 + q];
        acc_a = __hfma2(wv, *(const __half2*)&hw.x, acc_a);
        acc_b = __hfma2(wv, *(const __half2*)&hw.y, acc_b);
    }
    for (uint i = 64 + ep; i < deg; i += 8) {    // rare overflow tail
        const uint v  = __builtin_nontemporal_load(&vals[r0 + i]);
        const float uu = (float)(v & 32767u) * (1.0f / 32767.0f);
        const __half2 wv = __floats2half2_rn(1.0f - uu, uu);
        const uint2 hw = hp2[(size_t)(v >> 15) * 8 + q];
        acc_a = __hfma2(wv, *(const __half2*)&hw.x, acc_a);
        acc_b = __hfma2(wv, *(const __half2*)&hw.y, acc_b);
    }
    const float2 fa = __half22float2(acc_a);
    const float2 fb = __half22float2(acc_b);
    float a0 = fa.x + fa.y;            // Σ (1-u)*h0 + u*h1, feature 2q
    float a1 = fb.x + fb.y;            // feature 2q+1
    a0 += __shfl_xor(a0, 8); a0 += __shfl_xor(a0, 16); a0 += __shfl_xor(a0, 32);
    a1 += __shfl_xor(a1, 8); a1 += __shfl_xor(a1, 16); a1 += __shfl_xor(a1, 32);

    if (lane < 8)
        sum1[(size_t)n * 8 + lane] = make_float2(a0, a1);
}

// ---------------- dense per-node finalize: mean + ELU + layer-2 transforms -
__global__ __launch_bounds__(256) void k_mid2(
    const float2* __restrict__ sum1, const uint* __restrict__ rowptr,
    const float* __restrict__ r1,
    const float* __restrict__ W2, const float* __restrict__ root2,
    const float* __restrict__ b2,
    float4* __restrict__ h2, float2* __restrict__ r2)
{
    __shared__ float w2s[2 * F_HID * F_OUT];
    __shared__ float rts[F_HID * F_OUT];
    __shared__ float b2s[F_OUT];
    const int tid = threadIdx.x;
    if (tid < 2 * F_HID * F_OUT) w2s[tid] = W2[tid];
    if (tid < F_HID * F_OUT)     rts[tid] = root2[tid];
    if (tid < F_OUT)             b2s[tid] = b2[tid];
    __syncthreads();

    const int n = blockIdx.x * 256 + tid;
    if (n >= N_NODES) return;

    const uint deg = rowptr[n + 1] - rowptr[n];
    const float inv = 1.0f / (float)max(deg, 1u);

    float h[F_HID];
    #pragma unroll
    for (int k = 0; k < 8; ++k) {
        const float2 s = sum1[(size_t)n * 8 + k];
        const float v0 = s.x * inv + r1[(size_t)n * F_HID + 2 * k];
        const float v1 = s.y * inv + r1[(size_t)n * F_HID + 2 * k + 1];
        h[2 * k]     = (v0 > 0.0f) ? v0 : expm1f(v0);   // ELU
        h[2 * k + 1] = (v1 > 0.0f) ? v1 : expm1f(v1);
    }
    float o00 = 0.f, o01 = 0.f, o10 = 0.f, o11 = 0.f;
    float rr0 = b2s[0], rr1 = b2s[1];
    #pragma unroll
    for (int f = 0; f < F_HID; ++f) {
        o00 = fmaf(h[f], w2s[f * 2 + 0], o00);
        o01 = fmaf(h[f], w2s[f * 2 + 1], o01);
        o10 = fmaf(h[f], w2s[2 * F_HID + f * 2 + 0], o10);
        o11 = fmaf(h[f], w2s[2 * F_HID + f * 2 + 1], o11);
        rr0 = fmaf(h[f], rts[f * 2 + 0], rr0);
        rr1 = fmaf(h[f], rts[f * 2 + 1], rr1);
    }
    h2[n] = make_float4(o00, o10, o01, o11);   // [out0:(k0,k1), out1:(k0,k1)]
    r2[n] = make_float2(rr0, rr1);
}

// ---------------- layer-2 pull aggregate + log_softmax --------------------
// wave per node; lanes = 32 edge-slots x 2 features; LDS-staged u32 entries.
__global__ __launch_bounds__(256) void k_agg2(
    const uint* __restrict__ rowptr, const uint* __restrict__ vals,
    const float2* __restrict__ h2f2, const float2* __restrict__ r2,
    float* __restrict__ out)
{
    __shared__ uint ent[4][64];         // 1 KB
    const int tid = threadIdx.x;
    const int lane = tid & 63;
    const int wave = tid >> 6;
    const int n = blockIdx.x * 4 + wave;
    const int ep = lane >> 1;          // 0..31
    const int fp = lane & 1;           // feature

    const uint r0 = rowptr[n];
    const uint deg = rowptr[n + 1] - r0;
    const uint dcap = min(deg, 64u);

    if ((uint)lane < dcap)
        ent[wave][lane] = __builtin_nontemporal_load(&vals[r0 + lane]);
    __syncthreads();

    float acc = 0.f;
    #pragma unroll 2
    for (uint i = ep; i < dcap; i += 32) {
        const uint v  = ent[wave][i];
        const float uu = (float)(v & 32767u) * (1.0f / 32767.0f);
        const float2 g = h2f2[(size_t)(v >> 15) * 2 + fp];
        acc += (1.0f - uu) * g.x + uu * g.y;
    }
    for (uint i = 64 + ep; i < deg; i += 32) {   // rare overflow tail
        const uint v  = __builtin_nontemporal_load(&vals[r0 + i]);
        const float uu = (float)(v & 32767u) * (1.0f / 32767.0f);
        const float2 g = h2f2[(size_t)(v >> 15) * 2 + fp];
        acc += (1.0f - uu) * g.x + uu * g.y;
    }
    #pragma unroll
    for (int off = 2; off < 64; off <<= 1) acc += __shfl_xor(acc, off);

    const float inv = 1.0f / (float)max(deg, 1u);
    const float rv = fp ? r2[n].y : r2[n].x;
    const float o = acc * inv + rv;
    const float other = __shfl_xor(o, 1);
    const float m = fmaxf(o, other);
    const float l = m + logf(expf(o - m) + expf(other - m));
    if (lane < 2) out[(size_t)n * 2 + fp] = o - l;
}

extern "C" void kernel_launch(void* const* d_in, const int* in_sizes, int n_in,
                              void* d_out, int out_size, void* d_ws, size_t ws_size,
                              hipStream_t stream) {
    const float* x     = (const float*)d_in[0];
    const int*   ei    = (const int*)  d_in[1];   // [2][N_EDGES]
    const float* attr  = (const float*)d_in[2];
    const float* W1    = (const float*)d_in[4];
    const float* root1 = (const float*)d_in[5];
    const float* b1    = (const float*)d_in[6];
    const float* W2    = (const float*)d_in[7];
    const float* root2 = (const float*)d_in[8];
    const float* b2    = (const float*)d_in[9];
    float* out = (float*)d_out;

    char* ws = (char*)d_ws;
    size_t off = 0;
    uint*  vals   = (uint*) (ws + off); off += (size_t)N_EDGES * sizeof(uint);         // 12.8MB
    uint*  rowptr = (uint*) (ws + off); off += (size_t)(N_NODES + 1) * sizeof(uint);
    uint*  cnt    = (uint*) (ws + off); off += (size_t)NBUCK * HB * sizeof(uint);      // 200KB
    uint*  bstart = (uint*) (ws + off); off += (size_t)(NBUCK + 1) * sizeof(uint);
    uint*  tot    = (uint*) (ws + off); off += (size_t)NBUCK * sizeof(uint);
    off = (off + 255) & ~(size_t)255;
    uint2* buck   = (uint2*)(ws + off); off += (size_t)N_EDGES * sizeof(uint2);        // 25.6MB

    // buck is dead after k_fscatter; alias the node buffers onto it
    // (stream-ordered: k_transform1 launches after k_fscatter).
    char* alias = (char*)buck;
    size_t aoff = 0;
    __half2* hp = (__half2*)(alias + aoff); aoff += (size_t)N_NODES * F_HID * sizeof(__half2); // 6.4MB
    float*   r1 = (float*)  (alias + aoff); aoff += (size_t)N_NODES * F_HID * sizeof(float);   // 6.4MB
    float4*  h2 = (float4*) (alias + aoff); aoff += (size_t)N_NODES * sizeof(float4);          // 1.6MB
    float2*  r2 = (float2*) (alias + aoff); aoff += (size_t)N_NODES * sizeof(float2);          // 0.8MB
    float2* sum1= (float2*) (alias + aoff); aoff += (size_t)N_NODES * 8 * sizeof(float2);      // 6.4MB
    (void)ws_size;

    const int* esrc = ei;
    const int* edst = ei + N_EDGES;

    k_bhist    <<<HB, 1024, 0, stream>>>(edst, cnt);
    k_brow1    <<<NBUCK, 256, 0, stream>>>(cnt, tot);
    k_bexc     <<<1, 256, 0, stream>>>(tot, bstart);
    k_bscatter <<<HB, 1024, 0, stream>>>(esrc, edst, attr, cnt, bstart, buck);
    k_fscatter <<<NBUCK, 1024, 0, stream>>>(buck, bstart, rowptr, vals);
    k_transform1<<<(N_NODES + 127) / 128, 128, 0, stream>>>(x, W1, root1, b1, hp, r1);
    k_agg1     <<<N_NODES / 4, 256, 0, stream>>>(rowptr, vals, (const uint2*)hp, sum1);
    k_mid2     <<<(N_NODES + 255) / 256, 256, 0, stream>>>(sum1, rowptr, r1, W2, root2, b2, h2, r2);
    k_agg2     <<<N_NODES / 4, 256, 0, stream>>>(rowptr, vals, (const float2*)h2, r2, out);
}